// Round 11
// baseline (538.068 us; speedup 1.0000x reference)
//
#include <hip/hip_runtime.h>
#include <hip/hip_bf16.h>
#include <type_traits>

#define BN_EPS 1e-5f
#define BINSHIFT 8
#define BINW 256           // nodes per bin (coarse sort granularity)
#define NBLK 512           // chunks for the contention-free counting sort
#define NSEG 8
#define SEGW (NBLK / NSEG) // 64

// ---- bf16 helpers (RN rounding) ----
__device__ __forceinline__ unsigned pk_bf16(float x, float y) {
    unsigned ux = __float_as_uint(x);
    ux += 0x7FFFu + ((ux >> 16) & 1u);
    unsigned uy = __float_as_uint(y);
    uy += 0x7FFFu + ((uy >> 16) & 1u);
    return (ux >> 16) | (uy & 0xFFFF0000u);
}
__device__ __forceinline__ unsigned short f2bf(float x) {
    unsigned u = __float_as_uint(x);
    u += 0x7FFFu + ((u >> 16) & 1u);
    return (unsigned short)(u >> 16);
}
__device__ __forceinline__ float bfu(unsigned short u) {
    return __uint_as_float((unsigned)u << 16);
}
__device__ __forceinline__ float bf_lo(unsigned u) { return __uint_as_float(u << 16); }
__device__ __forceinline__ float bf_hi(unsigned u) { return __uint_as_float(u & 0xFFFF0000u); }

// ---- non-temporal vector loads (nt: no L2 alloc). SAFE ONLY for reads where
// a wave covers whole 64B lines exactly once (full-line streams). Poison for
// sub-line granule access (measured: +40 MB fetch on ea_sorted in gine, R5).
typedef float  f32x4_t __attribute__((ext_vector_type(4)));
typedef unsigned int u32x4_t __attribute__((ext_vector_type(4)));

__device__ __forceinline__ float4 nt_ld_f4(const float* p) {
    f32x4_t v = __builtin_nontemporal_load((const f32x4_t*)p);
    float4 r; r.x = v.x; r.y = v.y; r.z = v.z; r.w = v.w; return r;
}
__device__ __forceinline__ uint4 nt_ld_u4(const uint4* p) {
    u32x4_t v = __builtin_nontemporal_load((const u32x4_t*)p);
    uint4 r; r.x = v.x; r.y = v.y; r.z = v.z; r.w = v.w; return r;
}
__device__ __forceinline__ int nt_ld_i(const int* p) {
    return __builtin_nontemporal_load(p);
}

// XCD-aware chunk swizzle: chunks 0..63 -> XCD0, 64..127 -> XCD1, ... so
// adjacent chunks (adjacent write runs within a bin) share one L2.
__device__ __forceinline__ int chunk_of(int bid) {
    return ((bid & 7) << 6) | (bid >> 3);   // NBLK = 512
}

// ===========================================================================
// Preprocessing: LIGHTWEIGHT-KEY counting sort (4 B key dl<<21|e through both
// scatter passes; 20 B payload materialized once by apply_kernel).
// ===========================================================================

__global__ __launch_bounds__(256)
void hist2d_kernel(const int* __restrict__ dst, int* __restrict__ histmatT,
                   int E, int nbins, int chunk) {
    __shared__ int h[512];
    for (int i = threadIdx.x; i < nbins; i += 256) h[i] = 0;
    __syncthreads();
    int c = chunk_of(blockIdx.x);
    int e0 = c * chunk;
    int e1 = min(E, e0 + chunk);
    for (int e = e0 + threadIdx.x; e < e1; e += 256)
        atomicAdd(&h[nt_ld_i(dst + e) >> BINSHIFT], 1);
    __syncthreads();
    // transposed write: 4B at [bin][c]; same-XCD neighbor chunks share lines
    for (int i = threadIdx.x; i < nbins; i += 256)
        histmatT[(size_t)i * NBLK + c] = h[i];
}

// Per-bin totals + per-segment partials. Thread = bin, contiguous streams.
__global__ __launch_bounds__(256)
void colsum_kernel(const int* __restrict__ histmatT, int* __restrict__ bincnt,
                   int* __restrict__ segsum, int nbins) {
    int bin = blockIdx.x * 256 + threadIdx.x;
    if (bin >= nbins) return;
    const int* col = histmatT + (size_t)bin * NBLK;
    int tot = 0;
#pragma unroll
    for (int s = 0; s < NSEG; ++s) {
        int ps = 0;
#pragma unroll 16
        for (int r = 0; r < SEGW; ++r) ps += col[s * SEGW + r];
        segsum[s * nbins + bin] = ps;
        tot += ps;
    }
    bincnt[bin] = tot;
}

__global__ __launch_bounds__(1024)
void bin_scan_kernel(const int* __restrict__ bincnt, int* __restrict__ binstart,
                     int nbins, int E) {
    __shared__ int a[2048];
    __shared__ int b[1024];
    int t = threadIdx.x;
    a[t]        = (t < nbins) ? bincnt[t] : 0;
    a[t + 1024] = (t + 1024 < nbins) ? bincnt[t + 1024] : 0;
    __syncthreads();
    b[t] = a[2 * t] + a[2 * t + 1];
    __syncthreads();
    for (int off = 1; off < 1024; off <<= 1) {
        int v = (t >= off) ? b[t - off] : 0;
        __syncthreads();
        b[t] += v;
        __syncthreads();
    }
    int base = (t == 0) ? 0 : b[t - 1];
    if (2 * t < nbins)     binstart[2 * t]     = base;
    if (2 * t + 1 < nbins) binstart[2 * t + 1] = base + a[2 * t];
    if (t == 0) binstart[nbins] = E;
}

// Segmented serial scan: thread (bin, seg) streams its contiguous 64-chunk
// slice of histmatT and writes exclusive bases COALESCED into basemat.
__global__ __launch_bounds__(256)
void rowscan_kernel(const int* __restrict__ histmatT, const int* __restrict__ binstart,
                    const int* __restrict__ segsum, int* __restrict__ basemat,
                    int nbins) {
    int bin = blockIdx.x * 256 + threadIdx.x;
    if (bin >= nbins) return;
    int seg = blockIdx.y;
    int base = binstart[bin];
    for (int s = 0; s < seg; ++s) base += segsum[s * nbins + bin];
    const int* col = histmatT + (size_t)bin * NBLK + seg * SEGW;
#pragma unroll 8
    for (int r = 0; r < SEGW; ++r) {
        int v = col[r];
        basemat[(size_t)(seg * SEGW + r) * nbins + bin] = base;
        base += v;
    }
}

// Placement (lite): only the 4 B key (dl<<21 | e_orig) is scattered.
__global__ __launch_bounds__(512)
void place_kernel(const int* __restrict__ dst, const int* __restrict__ basemat,
                  int* __restrict__ tmp_word, int E, int nbins, int chunk) {
    __shared__ int cur[512];
    int c = chunk_of(blockIdx.x);
    const int* row = basemat + (size_t)c * nbins;
    for (int i = threadIdx.x; i < nbins; i += 512) cur[i] = row[i];
    __syncthreads();
    int e0 = c * chunk;
    int e1 = min(E, e0 + chunk);
    for (int e = e0 + threadIdx.x; e < e1; e += 512) {
        int d = nt_ld_i(dst + e);
        int bin = d >> BINSHIFT;
        int pos = atomicAdd(&cur[bin], 1);   // LDS atomic
        tmp_word[pos] = ((d & (BINW - 1)) << 21) | e;   // E < 2^21
    }
}

// Per-bin fine sort to node granularity (bin = 256 nodes). 4B keys only.
__global__ __launch_bounds__(256)
void pass2_kernel(const int* __restrict__ binstart, const int* __restrict__ tmp_word,
                  int* __restrict__ rowstart, int* __restrict__ perm,
                  int N, int E) {
    __shared__ int s_cur[BINW];   // 256
    __shared__ int s_wsum[4];
    int b = blockIdx.x;
    int node0 = b << BINSHIFT;
    int e0 = binstart[b], e1 = binstart[b + 1];
    int t = threadIdx.x;

    s_cur[t] = 0;
    __syncthreads();

    for (int e = e0 + t; e < e1; e += 256)
        atomicAdd(&s_cur[tmp_word[e] >> 21], 1);
    __syncthreads();

    int val = s_cur[t];
    int inc = val;
    int lane = t & 63, wv = t >> 6;
#pragma unroll
    for (int off = 1; off < 64; off <<= 1) {
        int n = __shfl_up(inc, off);
        if (lane >= off) inc += n;
    }
    if (lane == 63) s_wsum[wv] = inc;
    __syncthreads();
    int add = 0;
#pragma unroll
    for (int w2 = 0; w2 < 4; ++w2) add += (w2 < wv) ? s_wsum[w2] : 0;
    int excl = e0 + add + inc - val;
    s_cur[t] = excl;
    int node = node0 + t;
    if (node <= N) rowstart[node] = excl;
    __syncthreads();

    for (int e = e0 + t; e < e1; e += 256) {
        int wd = tmp_word[e];
        int dl = wd >> 21;
        int fpos = atomicAdd(&s_cur[dl], 1);
        perm[fpos] = wd & 0x1FFFFF;
    }
}

// Materialize sorted payload via the permutation.
__global__ __launch_bounds__(256)
void apply_kernel(const int* __restrict__ perm, const int* __restrict__ src,
                  const float* __restrict__ edge_attr,
                  int* __restrict__ src_sorted, uint4* __restrict__ ea_sorted,
                  int E) {
    int f = blockIdx.x * 256 + threadIdx.x;
    if (f >= E) return;
    int e = nt_ld_i(perm + f);
    src_sorted[f] = src[e];
    const float4* sp = (const float4*)(edge_attr + (size_t)e * 8);
    float4 a0 = sp[0], a1 = sp[1];
    uint4 pkd;
    pkd.x = pk_bf16(a0.x, a0.y);
    pkd.y = pk_bf16(a0.z, a0.w);
    pkd.z = pk_bf16(a1.x, a1.y);
    pkd.w = pk_bf16(a1.z, a1.w);
    ea_sorted[f] = pkd;
}

// ===========================================================================
// Fused GINE layer — NODE-PARALLEL WAVES + DEPTH-1 PIPELINE (measured best).
// Template HEAD: layer 3 computes the output head in-epilogue from fp32 h3
// in LDS + h1/h2 staged from global — no h3 store, no final_kernel.
// ===========================================================================
template<int DIN, int C, int S, int NPW, bool XBF, bool HEAD>
__global__ __launch_bounds__(256)
void gine_layer_wave(const void* __restrict__ xin_,      // [N, DIN] fp32|bf16
                     const int*   __restrict__ rowstart,   // [N+1]
                     const int*   __restrict__ src_sorted, // [E]
                     const uint4* __restrict__ ea_sorted,  // [E] bf16x8
                     const float* __restrict__ ew, const float* __restrict__ eb,
                     const float* __restrict__ wa, const float* __restrict__ ba,
                     const float* __restrict__ g, const float* __restrict__ be,
                     const float* __restrict__ m, const float* __restrict__ v,
                     const float* __restrict__ wb, const float* __restrict__ bb,
                     unsigned short* __restrict__ hout,    // [N, 16] bf16 (!HEAD)
                     const unsigned short* __restrict__ h1in, // [N,16] (HEAD)
                     const unsigned short* __restrict__ h2in, // [N,16] (HEAD)
                     const float* __restrict__ lw1, const float* __restrict__ lb1,
                     const float* __restrict__ lw2, const float* __restrict__ lb2,
                     float* __restrict__ out,              // [N, 4] (HEAD)
                     int N) {
    static_assert(C * S * NPW == 64 && C * 4 == DIN, "lane layout");
    constexpr int NB  = NPW * 4;   // nodes per block (4 waves)
    constexpr int PAD = DIN + 1;
    const float* xf = (const float*)xin_;
    const unsigned short* xb = (const unsigned short*)xin_;

    __shared__ float s_wa[DIN * 16];
    __shared__ float s_wb[256];
    __shared__ float s_ba[16], s_scale[16], s_shift[16], s_bb[16];
    __shared__ float s_s[NB * PAD];
    __shared__ float s_h[NB * 17];
    // head-only LDS (1-sized when unused)
    __shared__ float s_lw1[HEAD ? 48 * 64 : 1];
    __shared__ float s_lw2[HEAD ? 64 * 4 : 1];
    __shared__ float s_lb1[HEAD ? 64 : 1];
    __shared__ float s_lb2[HEAD ? 4 : 1];
    __shared__ float s_c12[HEAD ? NB * 33 : 1];   // h1|h2 fp32, pad 33
    __shared__ float s_o[HEAD ? NB * 17 : 1];     // h3 fp32

    int t = threadIdx.x;
    for (int idx = t; idx < DIN * 16; idx += 256) s_wa[idx] = wa[idx];
    s_wb[t] = wb[t];
    if (t < 16) {
        s_ba[t] = ba[t];
        float sc = g[t] * rsqrtf(v[t] + BN_EPS);
        s_scale[t] = sc;
        s_shift[t] = be[t] - m[t] * sc;
        s_bb[t] = bb[t];
    }
    if constexpr (HEAD) {
        for (int idx = t; idx < 48 * 64; idx += 256) s_lw1[idx] = lw1[idx];
        s_lw2[t] = lw2[t];
        if (t < 64) s_lb1[t] = lb1[t];
        if (t < 4) s_lb2[t] = lb2[t];
    }

    int w    = t >> 6;            // wave id (0..3)
    int lane = t & 63;
    int nlw  = lane / (C * S);    // node slot within wave (0..NPW-1)
    int r    = lane % (C * S);
    int c    = r % C;             // channel group — fastest-varying: coalesced x
    int s    = r / C;             // edge slot (0..S-1)
    int c0   = c * 4;

    float ew_r[8][4];
#pragma unroll
    for (int k = 0; k < 8; ++k) {
        float4 wv = *(const float4*)(ew + k * DIN + c0);
        ew_r[k][0] = wv.x; ew_r[k][1] = wv.y; ew_r[k][2] = wv.z; ew_r[k][3] = wv.w;
    }
    float4 ebv = *(const float4*)(eb + c0);
    float eb_r[4] = {ebv.x, ebv.y, ebv.z, ebv.w};

    int node0 = blockIdx.x * NB;
    int nl    = w * NPW + nlw;    // node within block
    int i     = node0 + nl;

    float acc[4] = {0.f, 0.f, 0.f, 0.f};
    if (i < N) {
        int e0 = rowstart[i];
        int e1 = rowstart[i + 1];
        int e  = e0 + s;
        int sv = (e < e1) ? src_sorted[e] : 0;
        for (; e < e1; e += S) {
            int en = e + S;
            int sv_next = (en < e1) ? src_sorted[en] : 0;  // prefetch
            uint4 ev = ea_sorted[e];
            float xr[4];
            if constexpr (XBF) {
                ushort4 xv = *(const ushort4*)(xb + (size_t)sv * DIN + c0);
                xr[0] = bfu(xv.x); xr[1] = bfu(xv.y);
                xr[2] = bfu(xv.z); xr[3] = bfu(xv.w);
            } else {
                float4 xv = *(const float4*)(xf + (size_t)sv * DIN + c0);
                xr[0] = xv.x; xr[1] = xv.y; xr[2] = xv.z; xr[3] = xv.w;
            }
            float av[8] = {bf_lo(ev.x), bf_hi(ev.x), bf_lo(ev.y), bf_hi(ev.y),
                           bf_lo(ev.z), bf_hi(ev.z), bf_lo(ev.w), bf_hi(ev.w)};
#pragma unroll
            for (int j = 0; j < 4; ++j) {
                float lin = eb_r[j];
#pragma unroll
                for (int k = 0; k < 8; ++k) lin = fmaf(av[k], ew_r[k][j], lin);
                lin += xr[j];
                acc[j] += (lin > 0.f ? lin : 0.f);
            }
            sv = sv_next;
        }
    }
    // reduce over edge slots: lanes differing only in s are XOR-C apart
#pragma unroll
    for (int mask = C * (S >> 1); mask >= C; mask >>= 1) {
#pragma unroll
        for (int j = 0; j < 4; ++j) acc[j] += __shfl_xor(acc[j], mask);
    }
    if (s == 0 && i < N) {
        float xi[4];
        if constexpr (XBF) {
            ushort4 xv = *(const ushort4*)(xb + (size_t)i * DIN + c0);
            xi[0] = bfu(xv.x); xi[1] = bfu(xv.y);
            xi[2] = bfu(xv.z); xi[3] = bfu(xv.w);
        } else {
            float4 xv = *(const float4*)(xf + (size_t)i * DIN + c0);
            xi[0] = xv.x; xi[1] = xv.y; xi[2] = xv.z; xi[3] = xv.w;
        }
        s_s[nl * PAD + c0 + 0] = acc[0] + xi[0];
        s_s[nl * PAD + c0 + 1] = acc[1] + xi[1];
        s_s[nl * PAD + c0 + 2] = acc[2] + xi[2];
        s_s[nl * PAD + c0 + 3] = acc[3] + xi[3];
    }
    // HEAD: stage h1/h2 (bf16->fp32) for the block's nodes while acc settles
    if constexpr (HEAD) {
        for (int task = t; task < NB * 16; task += 256) {
            int nl2 = task >> 4;
            int ch  = task & 15;
            int i2  = node0 + nl2;
            float v1 = 0.f, v2 = 0.f;
            if (i2 < N) {
                v1 = bfu(h1in[(size_t)i2 * 16 + ch]);
                v2 = bfu(h2in[(size_t)i2 * 16 + ch]);
            }
            s_c12[nl2 * 33 + ch]      = v1;
            s_c12[nl2 * 33 + 16 + ch] = v2;
        }
    }
    __syncthreads();

    // Linear1 + BN + ReLU: task = (node, out-channel)
    for (int task = t; task < NB * 16; task += 256) {
        int nl2 = task >> 4;
        int j   = task & 15;
        float a = s_ba[j];
#pragma unroll
        for (int k = 0; k < DIN; ++k)
            a = fmaf(s_s[nl2 * PAD + k], s_wa[k * 16 + j], a);
        a = a * s_scale[j] + s_shift[j];
        s_h[nl2 * 17 + j] = a > 0.f ? a : 0.f;
    }
    __syncthreads();

    // Linear2 + ReLU: to global (layers 1/2) or LDS (layer 3 head input)
    for (int task = t; task < NB * 16; task += 256) {
        int nl2 = task >> 4;
        int j   = task & 15;
        float o = s_bb[j];
#pragma unroll
        for (int k = 0; k < 16; ++k)
            o = fmaf(s_h[nl2 * 17 + k], s_wb[k * 16 + j], o);
        o = o > 0.f ? o : 0.f;
        if constexpr (HEAD) {
            s_o[nl2 * 17 + j] = o;                         // fp32 h3
        } else {
            int i2 = node0 + nl2;
            if (i2 < N) hout[(size_t)i2 * 16 + j] = f2bf(o);
        }
    }

    if constexpr (HEAD) {
        __syncthreads();
        // head: thread = (node nl3 = t>>3, lane l3 = t&7 -> 8 hidden each)
        int nl3 = t >> 3;
        int l3  = t & 7;
        int i3  = node0 + nl3;
        float o0 = 0.f, o1 = 0.f, o2 = 0.f, o3 = 0.f;
        if (i3 < N) {
#pragma unroll
            for (int jj = 0; jj < 8; ++jj) {
                int j = l3 * 8 + jj;
                float a = s_lb1[j];
#pragma unroll
                for (int k = 0; k < 32; ++k)
                    a = fmaf(s_c12[nl3 * 33 + k], s_lw1[k * 64 + j], a);
#pragma unroll
                for (int k = 0; k < 16; ++k)
                    a = fmaf(s_o[nl3 * 17 + k], s_lw1[(32 + k) * 64 + j], a);
                a = a > 0.f ? a : 0.f;
                o0 = fmaf(a, s_lw2[j * 4 + 0], o0);
                o1 = fmaf(a, s_lw2[j * 4 + 1], o1);
                o2 = fmaf(a, s_lw2[j * 4 + 2], o2);
                o3 = fmaf(a, s_lw2[j * 4 + 3], o3);
            }
        }
        // reduce over 8 lanes (within wave: node group spans lanes 8k..8k+7)
#pragma unroll
        for (int mask = 4; mask >= 1; mask >>= 1) {
            o0 += __shfl_xor(o0, mask);
            o1 += __shfl_xor(o1, mask);
            o2 += __shfl_xor(o2, mask);
            o3 += __shfl_xor(o3, mask);
        }
        if (i3 < N && l3 == 0) {
            float4 ov = {o0 + s_lb2[0], o1 + s_lb2[1], o2 + s_lb2[2], o3 + s_lb2[3]};
            *(float4*)(out + (size_t)i3 * 4) = ov;
        }
    }
}

// ===========================================================================
// Launch
// ===========================================================================
extern "C" void kernel_launch(void* const* d_in, const int* in_sizes, int n_in,
                              void* d_out, int out_size, void* d_ws, size_t ws_size,
                              hipStream_t stream) {
    const float* x  = (const float*)d_in[0];
    const int*   ei = (const int*)d_in[1];
    const float* ea = (const float*)d_in[2];
    const int N = in_sizes[0] / 32;
    const int E = in_sizes[1] / 2;
    const int* srci = ei;
    const int* dsti = ei + E;

    const float* lw1 = (const float*)d_in[33];
    const float* lb1 = (const float*)d_in[34];
    const float* lw2 = (const float*)d_in[35];
    const float* lb2 = (const float*)d_in[36];

    const int nbins = (N + BINW - 1) >> BINSHIFT;   // 391
    const int chunk = (E + NBLK - 1) / NBLK;        // 3125

    // Workspace. tmp_word + perm alias h1..h2 region safely (tmp dead after
    // pass2, perm dead after apply, h first written by layer 1).
    char* p = (char*)d_ws;
    int*   binstart   = (int*)p;   p += (size_t)(nbins + 1 + 3) / 4 * 16;
    int*   bincnt     = (int*)p;   p += (size_t)(nbins + 3) / 4 * 16;
    int*   segsum     = (int*)p;   p += (size_t)(NSEG * nbins + 3) / 4 * 16;
    int*   rowstart   = (int*)p;   p += (size_t)(N + 1 + 3) / 4 * 16;
    int*   histmatT   = (int*)p;   p += (size_t)NBLK * nbins * 4;
    int*   basemat    = (int*)p;   p += (size_t)NBLK * nbins * 4;
    int*   src_sorted = (int*)p;   p += (size_t)E * 4;
    uint4* ea_sorted  = (uint4*)p; p += (size_t)E * 16;
    char*  u          = p;
    int*   tmp_word   = (int*)u;                        // E*4
    int*   perm       = (int*)(u + (size_t)E * 4);      // E*4
    unsigned short* h1 = (unsigned short*)u;            // N*16*2 each
    unsigned short* h2 = h1 + (size_t)N * 16;

    // ---- Lightweight-key bin sort + fine sort + payload apply ----
    hist2d_kernel<<<NBLK, 256, 0, stream>>>(dsti, histmatT, E, nbins, chunk);
    colsum_kernel<<<(nbins + 255) / 256, 256, 0, stream>>>(histmatT, bincnt,
                                                           segsum, nbins);
    bin_scan_kernel<<<1, 1024, 0, stream>>>(bincnt, binstart, nbins, E);
    rowscan_kernel<<<dim3((nbins + 255) / 256, NSEG), 256, 0, stream>>>(
        histmatT, binstart, segsum, basemat, nbins);
    place_kernel<<<NBLK, 512, 0, stream>>>(dsti, basemat, tmp_word,
                                           E, nbins, chunk);
    pass2_kernel<<<nbins, 256, 0, stream>>>(binstart, tmp_word,
                                            rowstart, perm, N, E);
    apply_kernel<<<(E + 255) / 256, 256, 0, stream>>>(perm, srci, ea,
                                                      src_sorted, ea_sorted, E);

    // ---- Layers (node-parallel depth-1 pipelined waves; temporal loads) ----
    // layer 1: wave = 4 nodes x (C=8 x S=2), 16 nodes/block
    gine_layer_wave<32, 8, 2, 4, false, false><<<(N + 15) / 16, 256, 0, stream>>>(
        x, rowstart, src_sorted, ea_sorted,
        (const float*)d_in[3], (const float*)d_in[4],
        (const float*)d_in[5], (const float*)d_in[6],
        (const float*)d_in[7], (const float*)d_in[8],
        (const float*)d_in[9], (const float*)d_in[10],
        (const float*)d_in[11], (const float*)d_in[12], h1,
        nullptr, nullptr, nullptr, nullptr, nullptr, nullptr, nullptr, N);

    // layer 2: wave = 8 nodes x (C=4 x S=2), 32 nodes/block
    gine_layer_wave<16, 4, 2, 8, true, false><<<(N + 31) / 32, 256, 0, stream>>>(
        h1, rowstart, src_sorted, ea_sorted,
        (const float*)d_in[13], (const float*)d_in[14],
        (const float*)d_in[15], (const float*)d_in[16],
        (const float*)d_in[17], (const float*)d_in[18],
        (const float*)d_in[19], (const float*)d_in[20],
        (const float*)d_in[21], (const float*)d_in[22], h2,
        nullptr, nullptr, nullptr, nullptr, nullptr, nullptr, nullptr, N);

    // layer 3 + fused head: h3 stays fp32 in LDS; writes out directly
    gine_layer_wave<16, 4, 2, 8, true, true><<<(N + 31) / 32, 256, 0, stream>>>(
        h2, rowstart, src_sorted, ea_sorted,
        (const float*)d_in[23], (const float*)d_in[24],
        (const float*)d_in[25], (const float*)d_in[26],
        (const float*)d_in[27], (const float*)d_in[28],
        (const float*)d_in[29], (const float*)d_in[30],
        (const float*)d_in[31], (const float*)d_in[32], nullptr,
        h1, h2, lw1, lb1, lw2, lb2, (float*)d_out, N);
}

// Round 13
// 430.643 us; speedup vs baseline: 1.2495x; 1.2495x over previous
//
#include <hip/hip_runtime.h>
#include <hip/hip_bf16.h>
#include <type_traits>

#define BN_EPS 1e-5f
#define BINSHIFT 8
#define BINW 256           // nodes per bin (coarse sort granularity)
#define NBLK 512           // chunks for the contention-free counting sort
#define NSEG 8
#define SEGW (NBLK / NSEG) // 64

// ---- bf16 helpers (RN rounding) ----
__device__ __forceinline__ unsigned pk_bf16(float x, float y) {
    unsigned ux = __float_as_uint(x);
    ux += 0x7FFFu + ((ux >> 16) & 1u);
    unsigned uy = __float_as_uint(y);
    uy += 0x7FFFu + ((uy >> 16) & 1u);
    return (ux >> 16) | (uy & 0xFFFF0000u);
}
__device__ __forceinline__ unsigned short f2bf(float x) {
    unsigned u = __float_as_uint(x);
    u += 0x7FFFu + ((u >> 16) & 1u);
    return (unsigned short)(u >> 16);
}
__device__ __forceinline__ float bfu(unsigned short u) {
    return __uint_as_float((unsigned)u << 16);
}
__device__ __forceinline__ float bf_lo(unsigned u) { return __uint_as_float(u << 16); }
__device__ __forceinline__ float bf_hi(unsigned u) { return __uint_as_float(u & 0xFFFF0000u); }

// ---- non-temporal vector loads (nt: no L2 alloc). SAFE ONLY for reads where
// a wave covers whole 64B lines exactly once (full-line streams). Poison for
// sub-line granule access (measured: +40 MB fetch on ea_sorted in gine, R5).
typedef float  f32x4_t __attribute__((ext_vector_type(4)));
typedef unsigned int u32x4_t __attribute__((ext_vector_type(4)));

__device__ __forceinline__ float4 nt_ld_f4(const float* p) {
    f32x4_t v = __builtin_nontemporal_load((const f32x4_t*)p);
    float4 r; r.x = v.x; r.y = v.y; r.z = v.z; r.w = v.w; return r;
}
__device__ __forceinline__ uint4 nt_ld_u4(const uint4* p) {
    u32x4_t v = __builtin_nontemporal_load((const u32x4_t*)p);
    uint4 r; r.x = v.x; r.y = v.y; r.z = v.z; r.w = v.w; return r;
}
__device__ __forceinline__ int nt_ld_i(const int* p) {
    return __builtin_nontemporal_load(p);
}

// XCD-aware chunk swizzle: chunks 0..63 -> XCD0, 64..127 -> XCD1, ... so
// adjacent chunks (adjacent write runs within a bin) share one L2.
__device__ __forceinline__ int chunk_of(int bid) {
    return ((bid & 7) << 6) | (bid >> 3);   // NBLK = 512
}

// ===========================================================================
// Preprocessing: LIGHTWEIGHT-KEY counting sort. A 4 B key (dl<<21 | e_orig,
// E < 2^21) flows through place; pass2 fine-sorts keys AND materializes the
// 20 B payload (src + packed ea) directly at the final position — no perm
// array, no separate apply pass.
// ===========================================================================

__global__ __launch_bounds__(256)
void hist2d_kernel(const int* __restrict__ dst, int* __restrict__ histmatT,
                   int E, int nbins, int chunk) {
    __shared__ int h[512];
    for (int i = threadIdx.x; i < nbins; i += 256) h[i] = 0;
    __syncthreads();
    int c = chunk_of(blockIdx.x);
    int e0 = c * chunk;
    int e1 = min(E, e0 + chunk);
    for (int e = e0 + threadIdx.x; e < e1; e += 256)
        atomicAdd(&h[nt_ld_i(dst + e) >> BINSHIFT], 1);
    __syncthreads();
    // transposed write: 4B at [bin][c]; same-XCD neighbor chunks share lines
    for (int i = threadIdx.x; i < nbins; i += 256)
        histmatT[(size_t)i * NBLK + c] = h[i];
}

// Per-bin totals + per-segment partials. Thread = bin, contiguous streams.
__global__ __launch_bounds__(256)
void colsum_kernel(const int* __restrict__ histmatT, int* __restrict__ bincnt,
                   int* __restrict__ segsum, int nbins) {
    int bin = blockIdx.x * 256 + threadIdx.x;
    if (bin >= nbins) return;
    const int* col = histmatT + (size_t)bin * NBLK;
    int tot = 0;
#pragma unroll
    for (int s = 0; s < NSEG; ++s) {
        int ps = 0;
#pragma unroll 16
        for (int r = 0; r < SEGW; ++r) ps += col[s * SEGW + r];
        segsum[s * nbins + bin] = ps;
        tot += ps;
    }
    bincnt[bin] = tot;
}

__global__ __launch_bounds__(1024)
void bin_scan_kernel(const int* __restrict__ bincnt, int* __restrict__ binstart,
                     int nbins, int E) {
    __shared__ int a[2048];
    __shared__ int b[1024];
    int t = threadIdx.x;
    a[t]        = (t < nbins) ? bincnt[t] : 0;
    a[t + 1024] = (t + 1024 < nbins) ? bincnt[t + 1024] : 0;
    __syncthreads();
    b[t] = a[2 * t] + a[2 * t + 1];
    __syncthreads();
    for (int off = 1; off < 1024; off <<= 1) {
        int v = (t >= off) ? b[t - off] : 0;
        __syncthreads();
        b[t] += v;
        __syncthreads();
    }
    int base = (t == 0) ? 0 : b[t - 1];
    if (2 * t < nbins)     binstart[2 * t]     = base;
    if (2 * t + 1 < nbins) binstart[2 * t + 1] = base + a[2 * t];
    if (t == 0) binstart[nbins] = E;
}

// Segmented serial scan: thread (bin, seg) streams its contiguous 64-chunk
// slice of histmatT and writes exclusive bases COALESCED into basemat.
__global__ __launch_bounds__(256)
void rowscan_kernel(const int* __restrict__ histmatT, const int* __restrict__ binstart,
                    const int* __restrict__ segsum, int* __restrict__ basemat,
                    int nbins) {
    int bin = blockIdx.x * 256 + threadIdx.x;
    if (bin >= nbins) return;
    int seg = blockIdx.y;
    int base = binstart[bin];
    for (int s = 0; s < seg; ++s) base += segsum[s * nbins + bin];
    const int* col = histmatT + (size_t)bin * NBLK + seg * SEGW;
#pragma unroll 8
    for (int r = 0; r < SEGW; ++r) {
        int v = col[r];
        basemat[(size_t)(seg * SEGW + r) * nbins + bin] = base;
        base += v;
    }
}

// Placement (lite): only the 4 B key (dl<<21 | e_orig) is scattered.
__global__ __launch_bounds__(512)
void place_kernel(const int* __restrict__ dst, const int* __restrict__ basemat,
                  int* __restrict__ tmp_word, int E, int nbins, int chunk) {
    __shared__ int cur[512];
    int c = chunk_of(blockIdx.x);
    const int* row = basemat + (size_t)c * nbins;
    for (int i = threadIdx.x; i < nbins; i += 512) cur[i] = row[i];
    __syncthreads();
    int e0 = c * chunk;
    int e1 = min(E, e0 + chunk);
    for (int e = e0 + threadIdx.x; e < e1; e += 512) {
        int d = nt_ld_i(dst + e);
        int bin = d >> BINSHIFT;
        int pos = atomicAdd(&cur[bin], 1);   // LDS atomic
        tmp_word[pos] = ((d & (BINW - 1)) << 21) | e;   // E < 2^21
    }
}

// Per-bin fine sort to node granularity (bin = 256 nodes), fused with payload
// materialization: the scatter loop gathers src + edge_attr via the original
// edge index and writes them at the final sorted position. Scatter writes
// land in the bin's ~100 KB window (L2-resident).
__global__ __launch_bounds__(256)
void pass2_kernel(const int* __restrict__ binstart, const int* __restrict__ tmp_word,
                  const int* __restrict__ src, const float* __restrict__ edge_attr,
                  int* __restrict__ rowstart, int* __restrict__ src_sorted,
                  uint4* __restrict__ ea_sorted, int N, int E) {
    __shared__ int s_cur[BINW];   // 256
    __shared__ int s_wsum[4];
    int b = blockIdx.x;
    int node0 = b << BINSHIFT;
    int e0 = binstart[b], e1 = binstart[b + 1];
    int t = threadIdx.x;

    s_cur[t] = 0;
    __syncthreads();

    for (int e = e0 + t; e < e1; e += 256)
        atomicAdd(&s_cur[tmp_word[e] >> 21], 1);
    __syncthreads();

    // exclusive scan over 256 counts: per-wave shfl scan + cross-wave offsets
    int val = s_cur[t];
    int inc = val;
    int lane = t & 63, wv = t >> 6;
#pragma unroll
    for (int off = 1; off < 64; off <<= 1) {
        int n = __shfl_up(inc, off);
        if (lane >= off) inc += n;
    }
    if (lane == 63) s_wsum[wv] = inc;
    __syncthreads();
    int add = 0;
#pragma unroll
    for (int w2 = 0; w2 < 4; ++w2) add += (w2 < wv) ? s_wsum[w2] : 0;
    int excl = e0 + add + inc - val;
    s_cur[t] = excl;                       // each thread touches only slot t
    int node = node0 + t;
    if (node <= N) rowstart[node] = excl;
    __syncthreads();

    for (int e = e0 + t; e < e1; e += 256) {
        int wd = tmp_word[e];
        int dl = wd >> 21;                 // dl <= 255 -> word positive
        int eo = wd & 0x1FFFFF;            // original edge index
        int fpos = atomicAdd(&s_cur[dl], 1);
        src_sorted[fpos] = src[eo];
        const float4* sp = (const float4*)(edge_attr + (size_t)eo * 8);
        float4 a0 = sp[0], a1 = sp[1];
        uint4 pkd;
        pkd.x = pk_bf16(a0.x, a0.y);
        pkd.y = pk_bf16(a0.z, a0.w);
        pkd.z = pk_bf16(a1.x, a1.y);
        pkd.w = pk_bf16(a1.z, a1.w);
        ea_sorted[fpos] = pkd;
    }
}

// ===========================================================================
// Fused GINE layer — NODE-PARALLEL WAVES + DEPTH-1 PIPELINE (measured best:
// ~65 us/layer, R6/R10). TEMPORAL loads throughout — ea_sorted is consumed in
// 16B granules, so L2 line-merge across groups/iterations is essential.
// ===========================================================================
template<int DIN, int C, int S, int NPW, bool XBF>
__global__ __launch_bounds__(256)
void gine_layer_wave(const void* __restrict__ xin_,      // [N, DIN] fp32|bf16
                     const int*   __restrict__ rowstart,   // [N+1]
                     const int*   __restrict__ src_sorted, // [E]
                     const uint4* __restrict__ ea_sorted,  // [E] bf16x8
                     const float* __restrict__ ew, const float* __restrict__ eb,
                     const float* __restrict__ wa, const float* __restrict__ ba,
                     const float* __restrict__ g, const float* __restrict__ be,
                     const float* __restrict__ m, const float* __restrict__ v,
                     const float* __restrict__ wb, const float* __restrict__ bb,
                     unsigned short* __restrict__ hout,    // [N, 16] bf16
                     int N) {
    static_assert(C * S * NPW == 64 && C * 4 == DIN, "lane layout");
    constexpr int NB  = NPW * 4;   // nodes per block (4 waves)
    constexpr int PAD = DIN + 1;
    const float* xf = (const float*)xin_;
    const unsigned short* xb = (const unsigned short*)xin_;

    __shared__ float s_wa[DIN * 16];
    __shared__ float s_wb[256];
    __shared__ float s_ba[16], s_scale[16], s_shift[16], s_bb[16];
    __shared__ float s_s[NB * PAD];
    __shared__ float s_h[NB * 17];

    int t = threadIdx.x;
    for (int idx = t; idx < DIN * 16; idx += 256) s_wa[idx] = wa[idx];
    s_wb[t] = wb[t];
    if (t < 16) {
        s_ba[t] = ba[t];
        float sc = g[t] * rsqrtf(v[t] + BN_EPS);
        s_scale[t] = sc;
        s_shift[t] = be[t] - m[t] * sc;
        s_bb[t] = bb[t];
    }

    int w    = t >> 6;            // wave id (0..3)
    int lane = t & 63;
    int nlw  = lane / (C * S);    // node slot within wave (0..NPW-1)
    int r    = lane % (C * S);
    int c    = r % C;             // channel group — fastest-varying: coalesced x
    int s    = r / C;             // edge slot (0..S-1)
    int c0   = c * 4;

    float ew_r[8][4];
#pragma unroll
    for (int k = 0; k < 8; ++k) {
        float4 wv = *(const float4*)(ew + k * DIN + c0);
        ew_r[k][0] = wv.x; ew_r[k][1] = wv.y; ew_r[k][2] = wv.z; ew_r[k][3] = wv.w;
    }
    float4 ebv = *(const float4*)(eb + c0);
    float eb_r[4] = {ebv.x, ebv.y, ebv.z, ebv.w};

    int node0 = blockIdx.x * NB;
    int nl    = w * NPW + nlw;    // node within block
    int i     = node0 + nl;

    float acc[4] = {0.f, 0.f, 0.f, 0.f};
    if (i < N) {
        int e0 = rowstart[i];
        int e1 = rowstart[i + 1];
        int e  = e0 + s;
        int sv = (e < e1) ? src_sorted[e] : 0;
        for (; e < e1; e += S) {
            int en = e + S;
            int sv_next = (en < e1) ? src_sorted[en] : 0;  // prefetch
            uint4 ev = ea_sorted[e];
            float xr[4];
            if constexpr (XBF) {
                ushort4 xv = *(const ushort4*)(xb + (size_t)sv * DIN + c0);
                xr[0] = bfu(xv.x); xr[1] = bfu(xv.y);
                xr[2] = bfu(xv.z); xr[3] = bfu(xv.w);
            } else {
                float4 xv = *(const float4*)(xf + (size_t)sv * DIN + c0);
                xr[0] = xv.x; xr[1] = xv.y; xr[2] = xv.z; xr[3] = xv.w;
            }
            float av[8] = {bf_lo(ev.x), bf_hi(ev.x), bf_lo(ev.y), bf_hi(ev.y),
                           bf_lo(ev.z), bf_hi(ev.z), bf_lo(ev.w), bf_hi(ev.w)};
#pragma unroll
            for (int j = 0; j < 4; ++j) {
                float lin = eb_r[j];
#pragma unroll
                for (int k = 0; k < 8; ++k) lin = fmaf(av[k], ew_r[k][j], lin);
                lin += xr[j];
                acc[j] += (lin > 0.f ? lin : 0.f);
            }
            sv = sv_next;
        }
    }
    // reduce over edge slots: lanes differing only in s are XOR-C apart
#pragma unroll
    for (int mask = C * (S >> 1); mask >= C; mask >>= 1) {
#pragma unroll
        for (int j = 0; j < 4; ++j) acc[j] += __shfl_xor(acc[j], mask);
    }
    if (s == 0 && i < N) {
        float xi[4];
        if constexpr (XBF) {
            ushort4 xv = *(const ushort4*)(xb + (size_t)i * DIN + c0);
            xi[0] = bfu(xv.x); xi[1] = bfu(xv.y);
            xi[2] = bfu(xv.z); xi[3] = bfu(xv.w);
        } else {
            float4 xv = *(const float4*)(xf + (size_t)i * DIN + c0);
            xi[0] = xv.x; xi[1] = xv.y; xi[2] = xv.z; xi[3] = xv.w;
        }
        s_s[nl * PAD + c0 + 0] = acc[0] + xi[0];
        s_s[nl * PAD + c0 + 1] = acc[1] + xi[1];
        s_s[nl * PAD + c0 + 2] = acc[2] + xi[2];
        s_s[nl * PAD + c0 + 3] = acc[3] + xi[3];
    }
    __syncthreads();

    // Linear1 + BN + ReLU: task = (node, out-channel)
    for (int task = t; task < NB * 16; task += 256) {
        int nl2 = task >> 4;
        int j   = task & 15;
        float a = s_ba[j];
#pragma unroll
        for (int k = 0; k < DIN; ++k)
            a = fmaf(s_s[nl2 * PAD + k], s_wa[k * 16 + j], a);
        a = a * s_scale[j] + s_shift[j];
        s_h[nl2 * 17 + j] = a > 0.f ? a : 0.f;
    }
    __syncthreads();

    // Linear2 + ReLU + bf16 store
    for (int task = t; task < NB * 16; task += 256) {
        int nl2 = task >> 4;
        int j   = task & 15;
        float o = s_bb[j];
#pragma unroll
        for (int k = 0; k < 16; ++k)
            o = fmaf(s_h[nl2 * 17 + k], s_wb[k * 16 + j], o);
        o = o > 0.f ? o : 0.f;
        int i2 = node0 + nl2;
        if (i2 < N) hout[(size_t)i2 * 16 + j] = f2bf(o);  // coalesced 2B stores
    }
}

// ===========================================================================
// Head: bf16 h inputs.
// ===========================================================================
__global__ __launch_bounds__(256)
void final_kernel(const unsigned short* __restrict__ h1,
                  const unsigned short* __restrict__ h2,
                  const unsigned short* __restrict__ h3,
                  const float* __restrict__ lw1, const float* __restrict__ lb1,
                  const float* __restrict__ lw2, const float* __restrict__ lb2,
                  float* __restrict__ out, int N) {
    constexpr int NPB = 64;
    __shared__ float s_lw1[48 * 64];
    __shared__ float s_lw2[64 * 4];
    __shared__ float s_lb1[64];
    __shared__ float s_lb2[4];
    __shared__ float s_c[NPB][49];

    int t = threadIdx.x;
    for (int idx = t; idx < 48 * 64; idx += 256) s_lw1[idx] = lw1[idx];
    s_lw2[t] = lw2[t];
    if (t < 64) s_lb1[t] = lb1[t];
    if (t < 4) s_lb2[t] = lb2[t];

    int nl = t >> 2;
    int l  = t & 3;
    int i  = blockIdx.x * NPB + nl;

    if (i < N) {
        ushort4 c1 = *(const ushort4*)(h1 + (size_t)i * 16 + l * 4);
        ushort4 c2 = *(const ushort4*)(h2 + (size_t)i * 16 + l * 4);
        ushort4 c3 = *(const ushort4*)(h3 + (size_t)i * 16 + l * 4);
        s_c[nl][l * 4 + 0] = bfu(c1.x); s_c[nl][l * 4 + 1] = bfu(c1.y);
        s_c[nl][l * 4 + 2] = bfu(c1.z); s_c[nl][l * 4 + 3] = bfu(c1.w);
        s_c[nl][16 + l * 4 + 0] = bfu(c2.x); s_c[nl][16 + l * 4 + 1] = bfu(c2.y);
        s_c[nl][16 + l * 4 + 2] = bfu(c2.z); s_c[nl][16 + l * 4 + 3] = bfu(c2.w);
        s_c[nl][32 + l * 4 + 0] = bfu(c3.x); s_c[nl][32 + l * 4 + 1] = bfu(c3.y);
        s_c[nl][32 + l * 4 + 2] = bfu(c3.z); s_c[nl][32 + l * 4 + 3] = bfu(c3.w);
    }
    __syncthreads();

    float o0 = 0.f, o1 = 0.f, o2 = 0.f, o3 = 0.f;
    if (i < N) {
#pragma unroll 4
        for (int jj = 0; jj < 16; ++jj) {
            int j = l * 16 + jj;
            float a = s_lb1[j];
#pragma unroll
            for (int k = 0; k < 48; ++k) a = fmaf(s_c[nl][k], s_lw1[k * 64 + j], a);
            a = a > 0.f ? a : 0.f;
            o0 = fmaf(a, s_lw2[j * 4 + 0], o0);
            o1 = fmaf(a, s_lw2[j * 4 + 1], o1);
            o2 = fmaf(a, s_lw2[j * 4 + 2], o2);
            o3 = fmaf(a, s_lw2[j * 4 + 3], o3);
        }
    }
    o0 += __shfl_xor(o0, 1); o0 += __shfl_xor(o0, 2);
    o1 += __shfl_xor(o1, 1); o1 += __shfl_xor(o1, 2);
    o2 += __shfl_xor(o2, 1); o2 += __shfl_xor(o2, 2);
    o3 += __shfl_xor(o3, 1); o3 += __shfl_xor(o3, 2);
    if (i < N && l == 0) {
        float4 o = {o0 + s_lb2[0], o1 + s_lb2[1], o2 + s_lb2[2], o3 + s_lb2[3]};
        *(float4*)(out + (size_t)i * 4) = o;
    }
}

// ===========================================================================
// Launch
// ===========================================================================
extern "C" void kernel_launch(void* const* d_in, const int* in_sizes, int n_in,
                              void* d_out, int out_size, void* d_ws, size_t ws_size,
                              hipStream_t stream) {
    const float* x  = (const float*)d_in[0];
    const int*   ei = (const int*)d_in[1];
    const float* ea = (const float*)d_in[2];
    const int N = in_sizes[0] / 32;
    const int E = in_sizes[1] / 2;
    const int* srci = ei;
    const int* dsti = ei + E;

    const float* lw1 = (const float*)d_in[33];
    const float* lb1 = (const float*)d_in[34];
    const float* lw2 = (const float*)d_in[35];
    const float* lb2 = (const float*)d_in[36];

    const int nbins = (N + BINW - 1) >> BINSHIFT;   // 391
    const int chunk = (E + NBLK - 1) / NBLK;        // 3125

    // Workspace. tmp_word (6.4 MB) aliases h1..h3 region (tmp dead after
    // pass2, h first written by layer 1).
    char* p = (char*)d_ws;
    int*   binstart   = (int*)p;   p += (size_t)(nbins + 1 + 3) / 4 * 16;
    int*   bincnt     = (int*)p;   p += (size_t)(nbins + 3) / 4 * 16;
    int*   segsum     = (int*)p;   p += (size_t)(NSEG * nbins + 3) / 4 * 16;
    int*   rowstart   = (int*)p;   p += (size_t)(N + 1 + 3) / 4 * 16;
    int*   histmatT   = (int*)p;   p += (size_t)NBLK * nbins * 4;
    int*   basemat    = (int*)p;   p += (size_t)NBLK * nbins * 4;
    int*   src_sorted = (int*)p;   p += (size_t)E * 4;
    uint4* ea_sorted  = (uint4*)p; p += (size_t)E * 16;
    char*  u          = p;
    int*   tmp_word   = (int*)u;                        // E*4
    unsigned short* h1 = (unsigned short*)u;            // N*16*2 each
    unsigned short* h2 = h1 + (size_t)N * 16;
    unsigned short* h3 = h2 + (size_t)N * 16;

    // ---- Lightweight-key bin sort + fused fine-sort/payload-apply ----
    hist2d_kernel<<<NBLK, 256, 0, stream>>>(dsti, histmatT, E, nbins, chunk);
    colsum_kernel<<<(nbins + 255) / 256, 256, 0, stream>>>(histmatT, bincnt,
                                                           segsum, nbins);
    bin_scan_kernel<<<1, 1024, 0, stream>>>(bincnt, binstart, nbins, E);
    rowscan_kernel<<<dim3((nbins + 255) / 256, NSEG), 256, 0, stream>>>(
        histmatT, binstart, segsum, basemat, nbins);
    place_kernel<<<NBLK, 512, 0, stream>>>(dsti, basemat, tmp_word,
                                           E, nbins, chunk);
    pass2_kernel<<<nbins, 256, 0, stream>>>(binstart, tmp_word, srci, ea,
                                            rowstart, src_sorted, ea_sorted,
                                            N, E);

    // ---- Layers (node-parallel depth-1 pipelined waves; temporal loads) ----
    // layer 1: wave = 4 nodes x (C=8 x S=2), 16 nodes/block
    gine_layer_wave<32, 8, 2, 4, false><<<(N + 15) / 16, 256, 0, stream>>>(
        x, rowstart, src_sorted, ea_sorted,
        (const float*)d_in[3], (const float*)d_in[4],
        (const float*)d_in[5], (const float*)d_in[6],
        (const float*)d_in[7], (const float*)d_in[8],
        (const float*)d_in[9], (const float*)d_in[10],
        (const float*)d_in[11], (const float*)d_in[12], h1, N);

    // layers 2/3: wave = 8 nodes x (C=4 x S=2), 32 nodes/block
    gine_layer_wave<16, 4, 2, 8, true><<<(N + 31) / 32, 256, 0, stream>>>(
        h1, rowstart, src_sorted, ea_sorted,
        (const float*)d_in[13], (const float*)d_in[14],
        (const float*)d_in[15], (const float*)d_in[16],
        (const float*)d_in[17], (const float*)d_in[18],
        (const float*)d_in[19], (const float*)d_in[20],
        (const float*)d_in[21], (const float*)d_in[22], h2, N);

    gine_layer_wave<16, 4, 2, 8, true><<<(N + 31) / 32, 256, 0, stream>>>(
        h2, rowstart, src_sorted, ea_sorted,
        (const float*)d_in[23], (const float*)d_in[24],
        (const float*)d_in[25], (const float*)d_in[26],
        (const float*)d_in[27], (const float*)d_in[28],
        (const float*)d_in[29], (const float*)d_in[30],
        (const float*)d_in[31], (const float*)d_in[32], h3, N);

    // ---- Head ----
    final_kernel<<<(N + 63) / 64, 256, 0, stream>>>(
        h1, h2, h3, lw1, lb1, lw2, lb2, (float*)d_out, N);
}

// Round 14
// 406.227 us; speedup vs baseline: 1.3246x; 1.0601x over previous
//
#include <hip/hip_runtime.h>
#include <hip/hip_bf16.h>
#include <type_traits>

#define BN_EPS 1e-5f
#define BINSHIFT 8
#define BINW 256           // nodes per bin (coarse sort granularity)
#define NBLK 512           // chunks for the contention-free counting sort
#define NSEG 8
#define SEGW (NBLK / NSEG) // 64
#define ECAP2 5120         // LDS payload staging capacity (mean 4096 + 16 sigma)

// ---- bf16 helpers (RN rounding) ----
__device__ __forceinline__ unsigned pk_bf16(float x, float y) {
    unsigned ux = __float_as_uint(x);
    ux += 0x7FFFu + ((ux >> 16) & 1u);
    unsigned uy = __float_as_uint(y);
    uy += 0x7FFFu + ((uy >> 16) & 1u);
    return (ux >> 16) | (uy & 0xFFFF0000u);
}
__device__ __forceinline__ unsigned short f2bf(float x) {
    unsigned u = __float_as_uint(x);
    u += 0x7FFFu + ((u >> 16) & 1u);
    return (unsigned short)(u >> 16);
}
__device__ __forceinline__ float bfu(unsigned short u) {
    return __uint_as_float((unsigned)u << 16);
}
__device__ __forceinline__ float bf_lo(unsigned u) { return __uint_as_float(u << 16); }
__device__ __forceinline__ float bf_hi(unsigned u) { return __uint_as_float(u & 0xFFFF0000u); }

// ---- non-temporal vector loads (nt: no L2 alloc). SAFE ONLY for reads where
// a wave covers whole 64B lines exactly once (full-line streams). Poison for
// sub-line granule access (measured: +40 MB fetch on ea_sorted in gine, R5).
typedef float  f32x4_t __attribute__((ext_vector_type(4)));
typedef unsigned int u32x4_t __attribute__((ext_vector_type(4)));

__device__ __forceinline__ float4 nt_ld_f4(const float* p) {
    f32x4_t v = __builtin_nontemporal_load((const f32x4_t*)p);
    float4 r; r.x = v.x; r.y = v.y; r.z = v.z; r.w = v.w; return r;
}
__device__ __forceinline__ uint4 nt_ld_u4(const uint4* p) {
    u32x4_t v = __builtin_nontemporal_load((const u32x4_t*)p);
    uint4 r; r.x = v.x; r.y = v.y; r.z = v.z; r.w = v.w; return r;
}
__device__ __forceinline__ int nt_ld_i(const int* p) {
    return __builtin_nontemporal_load(p);
}

// XCD-aware chunk swizzle: chunks 0..63 -> XCD0, 64..127 -> XCD1, ... so
// adjacent chunks (adjacent write runs within a bin) share one L2.
__device__ __forceinline__ int chunk_of(int bid) {
    return ((bid & 7) << 6) | (bid >> 3);   // NBLK = 512
}

// ===========================================================================
// Preprocessing: LIGHTWEIGHT-KEY counting sort. A 4 B key (dl<<21 | e_orig,
// E < 2^21) flows through place; pass2 fine-sorts keys, gathers the payload,
// stages it in LDS at the final LOCAL position, then streams it out in
// full-line coalesced writes (kills scatter write-amp + RMW-allocate fetch).
// ===========================================================================

__global__ __launch_bounds__(256)
void hist2d_kernel(const int* __restrict__ dst, int* __restrict__ histmatT,
                   int E, int nbins, int chunk) {
    __shared__ int h[512];
    for (int i = threadIdx.x; i < nbins; i += 256) h[i] = 0;
    __syncthreads();
    int c = chunk_of(blockIdx.x);
    int e0 = c * chunk;
    int e1 = min(E, e0 + chunk);
    for (int e = e0 + threadIdx.x; e < e1; e += 256)
        atomicAdd(&h[nt_ld_i(dst + e) >> BINSHIFT], 1);
    __syncthreads();
    // transposed write: 4B at [bin][c]; same-XCD neighbor chunks share lines
    for (int i = threadIdx.x; i < nbins; i += 256)
        histmatT[(size_t)i * NBLK + c] = h[i];
}

// Per-bin totals + per-segment partials. Thread = bin, contiguous streams.
__global__ __launch_bounds__(256)
void colsum_kernel(const int* __restrict__ histmatT, int* __restrict__ bincnt,
                   int* __restrict__ segsum, int nbins) {
    int bin = blockIdx.x * 256 + threadIdx.x;
    if (bin >= nbins) return;
    const int* col = histmatT + (size_t)bin * NBLK;
    int tot = 0;
#pragma unroll
    for (int s = 0; s < NSEG; ++s) {
        int ps = 0;
#pragma unroll 16
        for (int r = 0; r < SEGW; ++r) ps += col[s * SEGW + r];
        segsum[s * nbins + bin] = ps;
        tot += ps;
    }
    bincnt[bin] = tot;
}

__global__ __launch_bounds__(1024)
void bin_scan_kernel(const int* __restrict__ bincnt, int* __restrict__ binstart,
                     int nbins, int E) {
    __shared__ int a[2048];
    __shared__ int b[1024];
    int t = threadIdx.x;
    a[t]        = (t < nbins) ? bincnt[t] : 0;
    a[t + 1024] = (t + 1024 < nbins) ? bincnt[t + 1024] : 0;
    __syncthreads();
    b[t] = a[2 * t] + a[2 * t + 1];
    __syncthreads();
    for (int off = 1; off < 1024; off <<= 1) {
        int v = (t >= off) ? b[t - off] : 0;
        __syncthreads();
        b[t] += v;
        __syncthreads();
    }
    int base = (t == 0) ? 0 : b[t - 1];
    if (2 * t < nbins)     binstart[2 * t]     = base;
    if (2 * t + 1 < nbins) binstart[2 * t + 1] = base + a[2 * t];
    if (t == 0) binstart[nbins] = E;
}

// Segmented serial scan: thread (bin, seg) streams its contiguous 64-chunk
// slice of histmatT and writes exclusive bases COALESCED into basemat.
__global__ __launch_bounds__(256)
void rowscan_kernel(const int* __restrict__ histmatT, const int* __restrict__ binstart,
                    const int* __restrict__ segsum, int* __restrict__ basemat,
                    int nbins) {
    int bin = blockIdx.x * 256 + threadIdx.x;
    if (bin >= nbins) return;
    int seg = blockIdx.y;
    int base = binstart[bin];
    for (int s = 0; s < seg; ++s) base += segsum[s * nbins + bin];
    const int* col = histmatT + (size_t)bin * NBLK + seg * SEGW;
#pragma unroll 8
    for (int r = 0; r < SEGW; ++r) {
        int v = col[r];
        basemat[(size_t)(seg * SEGW + r) * nbins + bin] = base;
        base += v;
    }
}

// Placement (lite): only the 4 B key (dl<<21 | e_orig) is scattered.
__global__ __launch_bounds__(512)
void place_kernel(const int* __restrict__ dst, const int* __restrict__ basemat,
                  int* __restrict__ tmp_word, int E, int nbins, int chunk) {
    __shared__ int cur[512];
    int c = chunk_of(blockIdx.x);
    const int* row = basemat + (size_t)c * nbins;
    for (int i = threadIdx.x; i < nbins; i += 512) cur[i] = row[i];
    __syncthreads();
    int e0 = c * chunk;
    int e1 = min(E, e0 + chunk);
    for (int e = e0 + threadIdx.x; e < e1; e += 512) {
        int d = nt_ld_i(dst + e);
        int bin = d >> BINSHIFT;
        int pos = atomicAdd(&cur[bin], 1);   // LDS atomic
        tmp_word[pos] = ((d & (BINW - 1)) << 21) | e;   // E < 2^21
    }
}

// Per-bin fine sort + payload apply with LDS STAGING: gather payload to LDS
// at the sorted LOCAL position, then stream out full-line coalesced.
// 512 threads (8 waves) for gather-latency hiding; ~103 KB LDS -> 1 block/CU.
// Fallback: bins larger than ECAP2 write payload directly (correct, slower).
__global__ __launch_bounds__(512)
void pass2_kernel(const int* __restrict__ binstart, const int* __restrict__ tmp_word,
                  const int* __restrict__ src, const float* __restrict__ edge_attr,
                  int* __restrict__ rowstart, int* __restrict__ src_sorted,
                  uint4* __restrict__ ea_sorted, int N, int E) {
    __shared__ int   s_cur[BINW];    // 256 cursors (absolute fpos)
    __shared__ int   s_wsum[4];
    __shared__ int   s_src[ECAP2];   // 20 KB
    __shared__ uint4 s_ea[ECAP2];    // 80 KB
    int b = blockIdx.x;
    int node0 = b << BINSHIFT;
    int e0 = binstart[b], e1 = binstart[b + 1];
    int cnt = e1 - e0;
    bool fits = (cnt <= ECAP2);
    int t = threadIdx.x;

    if (t < BINW) s_cur[t] = 0;
    __syncthreads();

    for (int e = e0 + t; e < e1; e += 512)
        atomicAdd(&s_cur[tmp_word[e] >> 21], 1);
    __syncthreads();

    // exclusive scan over 256 counts (threads 0..255 = waves 0..3)
    int val = 0, inc = 0;
    int lane = t & 63, wv = t >> 6;
    if (t < BINW) {
        val = s_cur[t];
        inc = val;
#pragma unroll
        for (int off = 1; off < 64; off <<= 1) {
            int n = __shfl_up(inc, off);
            if (lane >= off) inc += n;
        }
        if (lane == 63) s_wsum[wv] = inc;
    }
    __syncthreads();
    if (t < BINW) {
        int add = 0;
#pragma unroll
        for (int w2 = 0; w2 < 4; ++w2) add += (w2 < wv) ? s_wsum[w2] : 0;
        int excl = e0 + add + inc - val;
        s_cur[t] = excl;                   // absolute fpos cursor
        int node = node0 + t;
        if (node <= N) rowstart[node] = excl;
    }
    __syncthreads();

    // gather payload and scatter into LDS at local sorted position
    for (int e = e0 + t; e < e1; e += 512) {
        int wd = tmp_word[e];
        int dl = wd >> 21;                 // dl <= 255 -> word positive
        int eo = wd & 0x1FFFFF;            // original edge index
        int fpos = atomicAdd(&s_cur[dl], 1);
        int sv = src[eo];
        const float4* sp = (const float4*)(edge_attr + (size_t)eo * 8);
        float4 a0 = sp[0], a1 = sp[1];
        uint4 pkd;
        pkd.x = pk_bf16(a0.x, a0.y);
        pkd.y = pk_bf16(a0.z, a0.w);
        pkd.z = pk_bf16(a1.x, a1.y);
        pkd.w = pk_bf16(a1.z, a1.w);
        if (fits) {
            int li = fpos - e0;
            s_src[li] = sv;
            s_ea[li]  = pkd;
        } else {
            src_sorted[fpos] = sv;
            ea_sorted[fpos]  = pkd;
        }
    }
    __syncthreads();

    // stream LDS -> global: fully coalesced, full-line writes
    if (fits) {
        for (int idx = t; idx < cnt; idx += 512) {
            src_sorted[e0 + idx] = s_src[idx];
            ea_sorted[e0 + idx]  = s_ea[idx];
        }
    }
}

// ===========================================================================
// Fused GINE layer — NODE-PARALLEL WAVES + DEPTH-1 PIPELINE (measured best:
// ~65 us/layer, R6/R10). TEMPORAL loads throughout — ea_sorted is consumed in
// 16B granules, so L2 line-merge across groups/iterations is essential.
// ===========================================================================
template<int DIN, int C, int S, int NPW, bool XBF>
__global__ __launch_bounds__(256)
void gine_layer_wave(const void* __restrict__ xin_,      // [N, DIN] fp32|bf16
                     const int*   __restrict__ rowstart,   // [N+1]
                     const int*   __restrict__ src_sorted, // [E]
                     const uint4* __restrict__ ea_sorted,  // [E] bf16x8
                     const float* __restrict__ ew, const float* __restrict__ eb,
                     const float* __restrict__ wa, const float* __restrict__ ba,
                     const float* __restrict__ g, const float* __restrict__ be,
                     const float* __restrict__ m, const float* __restrict__ v,
                     const float* __restrict__ wb, const float* __restrict__ bb,
                     unsigned short* __restrict__ hout,    // [N, 16] bf16
                     int N) {
    static_assert(C * S * NPW == 64 && C * 4 == DIN, "lane layout");
    constexpr int NB  = NPW * 4;   // nodes per block (4 waves)
    constexpr int PAD = DIN + 1;
    const float* xf = (const float*)xin_;
    const unsigned short* xb = (const unsigned short*)xin_;

    __shared__ float s_wa[DIN * 16];
    __shared__ float s_wb[256];
    __shared__ float s_ba[16], s_scale[16], s_shift[16], s_bb[16];
    __shared__ float s_s[NB * PAD];
    __shared__ float s_h[NB * 17];

    int t = threadIdx.x;
    for (int idx = t; idx < DIN * 16; idx += 256) s_wa[idx] = wa[idx];
    s_wb[t] = wb[t];
    if (t < 16) {
        s_ba[t] = ba[t];
        float sc = g[t] * rsqrtf(v[t] + BN_EPS);
        s_scale[t] = sc;
        s_shift[t] = be[t] - m[t] * sc;
        s_bb[t] = bb[t];
    }

    int w    = t >> 6;            // wave id (0..3)
    int lane = t & 63;
    int nlw  = lane / (C * S);    // node slot within wave (0..NPW-1)
    int r    = lane % (C * S);
    int c    = r % C;             // channel group — fastest-varying: coalesced x
    int s    = r / C;             // edge slot (0..S-1)
    int c0   = c * 4;

    float ew_r[8][4];
#pragma unroll
    for (int k = 0; k < 8; ++k) {
        float4 wv = *(const float4*)(ew + k * DIN + c0);
        ew_r[k][0] = wv.x; ew_r[k][1] = wv.y; ew_r[k][2] = wv.z; ew_r[k][3] = wv.w;
    }
    float4 ebv = *(const float4*)(eb + c0);
    float eb_r[4] = {ebv.x, ebv.y, ebv.z, ebv.w};

    int node0 = blockIdx.x * NB;
    int nl    = w * NPW + nlw;    // node within block
    int i     = node0 + nl;

    float acc[4] = {0.f, 0.f, 0.f, 0.f};
    if (i < N) {
        int e0 = rowstart[i];
        int e1 = rowstart[i + 1];
        int e  = e0 + s;
        int sv = (e < e1) ? src_sorted[e] : 0;
        for (; e < e1; e += S) {
            int en = e + S;
            int sv_next = (en < e1) ? src_sorted[en] : 0;  // prefetch
            uint4 ev = ea_sorted[e];
            float xr[4];
            if constexpr (XBF) {
                ushort4 xv = *(const ushort4*)(xb + (size_t)sv * DIN + c0);
                xr[0] = bfu(xv.x); xr[1] = bfu(xv.y);
                xr[2] = bfu(xv.z); xr[3] = bfu(xv.w);
            } else {
                float4 xv = *(const float4*)(xf + (size_t)sv * DIN + c0);
                xr[0] = xv.x; xr[1] = xv.y; xr[2] = xv.z; xr[3] = xv.w;
            }
            float av[8] = {bf_lo(ev.x), bf_hi(ev.x), bf_lo(ev.y), bf_hi(ev.y),
                           bf_lo(ev.z), bf_hi(ev.z), bf_lo(ev.w), bf_hi(ev.w)};
#pragma unroll
            for (int j = 0; j < 4; ++j) {
                float lin = eb_r[j];
#pragma unroll
                for (int k = 0; k < 8; ++k) lin = fmaf(av[k], ew_r[k][j], lin);
                lin += xr[j];
                acc[j] += (lin > 0.f ? lin : 0.f);
            }
            sv = sv_next;
        }
    }
    // reduce over edge slots: lanes differing only in s are XOR-C apart
#pragma unroll
    for (int mask = C * (S >> 1); mask >= C; mask >>= 1) {
#pragma unroll
        for (int j = 0; j < 4; ++j) acc[j] += __shfl_xor(acc[j], mask);
    }
    if (s == 0 && i < N) {
        float xi[4];
        if constexpr (XBF) {
            ushort4 xv = *(const ushort4*)(xb + (size_t)i * DIN + c0);
            xi[0] = bfu(xv.x); xi[1] = bfu(xv.y);
            xi[2] = bfu(xv.z); xi[3] = bfu(xv.w);
        } else {
            float4 xv = *(const float4*)(xf + (size_t)i * DIN + c0);
            xi[0] = xv.x; xi[1] = xv.y; xi[2] = xv.z; xi[3] = xv.w;
        }
        s_s[nl * PAD + c0 + 0] = acc[0] + xi[0];
        s_s[nl * PAD + c0 + 1] = acc[1] + xi[1];
        s_s[nl * PAD + c0 + 2] = acc[2] + xi[2];
        s_s[nl * PAD + c0 + 3] = acc[3] + xi[3];
    }
    __syncthreads();

    // Linear1 + BN + ReLU: task = (node, out-channel)
    for (int task = t; task < NB * 16; task += 256) {
        int nl2 = task >> 4;
        int j   = task & 15;
        float a = s_ba[j];
#pragma unroll
        for (int k = 0; k < DIN; ++k)
            a = fmaf(s_s[nl2 * PAD + k], s_wa[k * 16 + j], a);
        a = a * s_scale[j] + s_shift[j];
        s_h[nl2 * 17 + j] = a > 0.f ? a : 0.f;
    }
    __syncthreads();

    // Linear2 + ReLU + bf16 store
    for (int task = t; task < NB * 16; task += 256) {
        int nl2 = task >> 4;
        int j   = task & 15;
        float o = s_bb[j];
#pragma unroll
        for (int k = 0; k < 16; ++k)
            o = fmaf(s_h[nl2 * 17 + k], s_wb[k * 16 + j], o);
        o = o > 0.f ? o : 0.f;
        int i2 = node0 + nl2;
        if (i2 < N) hout[(size_t)i2 * 16 + j] = f2bf(o);  // coalesced 2B stores
    }
}

// ===========================================================================
// Head: bf16 h inputs.
// ===========================================================================
__global__ __launch_bounds__(256)
void final_kernel(const unsigned short* __restrict__ h1,
                  const unsigned short* __restrict__ h2,
                  const unsigned short* __restrict__ h3,
                  const float* __restrict__ lw1, const float* __restrict__ lb1,
                  const float* __restrict__ lw2, const float* __restrict__ lb2,
                  float* __restrict__ out, int N) {
    constexpr int NPB = 64;
    __shared__ float s_lw1[48 * 64];
    __shared__ float s_lw2[64 * 4];
    __shared__ float s_lb1[64];
    __shared__ float s_lb2[4];
    __shared__ float s_c[NPB][49];

    int t = threadIdx.x;
    for (int idx = t; idx < 48 * 64; idx += 256) s_lw1[idx] = lw1[idx];
    s_lw2[t] = lw2[t];
    if (t < 64) s_lb1[t] = lb1[t];
    if (t < 4) s_lb2[t] = lb2[t];

    int nl = t >> 2;
    int l  = t & 3;
    int i  = blockIdx.x * NPB + nl;

    if (i < N) {
        ushort4 c1 = *(const ushort4*)(h1 + (size_t)i * 16 + l * 4);
        ushort4 c2 = *(const ushort4*)(h2 + (size_t)i * 16 + l * 4);
        ushort4 c3 = *(const ushort4*)(h3 + (size_t)i * 16 + l * 4);
        s_c[nl][l * 4 + 0] = bfu(c1.x); s_c[nl][l * 4 + 1] = bfu(c1.y);
        s_c[nl][l * 4 + 2] = bfu(c1.z); s_c[nl][l * 4 + 3] = bfu(c1.w);
        s_c[nl][16 + l * 4 + 0] = bfu(c2.x); s_c[nl][16 + l * 4 + 1] = bfu(c2.y);
        s_c[nl][16 + l * 4 + 2] = bfu(c2.z); s_c[nl][16 + l * 4 + 3] = bfu(c2.w);
        s_c[nl][32 + l * 4 + 0] = bfu(c3.x); s_c[nl][32 + l * 4 + 1] = bfu(c3.y);
        s_c[nl][32 + l * 4 + 2] = bfu(c3.z); s_c[nl][32 + l * 4 + 3] = bfu(c3.w);
    }
    __syncthreads();

    float o0 = 0.f, o1 = 0.f, o2 = 0.f, o3 = 0.f;
    if (i < N) {
#pragma unroll 4
        for (int jj = 0; jj < 16; ++jj) {
            int j = l * 16 + jj;
            float a = s_lb1[j];
#pragma unroll
            for (int k = 0; k < 48; ++k) a = fmaf(s_c[nl][k], s_lw1[k * 64 + j], a);
            a = a > 0.f ? a : 0.f;
            o0 = fmaf(a, s_lw2[j * 4 + 0], o0);
            o1 = fmaf(a, s_lw2[j * 4 + 1], o1);
            o2 = fmaf(a, s_lw2[j * 4 + 2], o2);
            o3 = fmaf(a, s_lw2[j * 4 + 3], o3);
        }
    }
    o0 += __shfl_xor(o0, 1); o0 += __shfl_xor(o0, 2);
    o1 += __shfl_xor(o1, 1); o1 += __shfl_xor(o1, 2);
    o2 += __shfl_xor(o2, 1); o2 += __shfl_xor(o2, 2);
    o3 += __shfl_xor(o3, 1); o3 += __shfl_xor(o3, 2);
    if (i < N && l == 0) {
        float4 o = {o0 + s_lb2[0], o1 + s_lb2[1], o2 + s_lb2[2], o3 + s_lb2[3]};
        *(float4*)(out + (size_t)i * 4) = o;
    }
}

// ===========================================================================
// Launch
// ===========================================================================
extern "C" void kernel_launch(void* const* d_in, const int* in_sizes, int n_in,
                              void* d_out, int out_size, void* d_ws, size_t ws_size,
                              hipStream_t stream) {
    const float* x  = (const float*)d_in[0];
    const int*   ei = (const int*)d_in[1];
    const float* ea = (const float*)d_in[2];
    const int N = in_sizes[0] / 32;
    const int E = in_sizes[1] / 2;
    const int* srci = ei;
    const int* dsti = ei + E;

    const float* lw1 = (const float*)d_in[33];
    const float* lb1 = (const float*)d_in[34];
    const float* lw2 = (const float*)d_in[35];
    const float* lb2 = (const float*)d_in[36];

    const int nbins = (N + BINW - 1) >> BINSHIFT;   // 391
    const int chunk = (E + NBLK - 1) / NBLK;        // 3125

    // Workspace. tmp_word (6.4 MB) aliases h1..h3 region (tmp dead after
    // pass2, h first written by layer 1).
    char* p = (char*)d_ws;
    int*   binstart   = (int*)p;   p += (size_t)(nbins + 1 + 3) / 4 * 16;
    int*   bincnt     = (int*)p;   p += (size_t)(nbins + 3) / 4 * 16;
    int*   segsum     = (int*)p;   p += (size_t)(NSEG * nbins + 3) / 4 * 16;
    int*   rowstart   = (int*)p;   p += (size_t)(N + 1 + 3) / 4 * 16;
    int*   histmatT   = (int*)p;   p += (size_t)NBLK * nbins * 4;
    int*   basemat    = (int*)p;   p += (size_t)NBLK * nbins * 4;
    int*   src_sorted = (int*)p;   p += (size_t)E * 4;
    uint4* ea_sorted  = (uint4*)p; p += (size_t)E * 16;
    char*  u          = p;
    int*   tmp_word   = (int*)u;                        // E*4
    unsigned short* h1 = (unsigned short*)u;            // N*16*2 each
    unsigned short* h2 = h1 + (size_t)N * 16;
    unsigned short* h3 = h2 + (size_t)N * 16;

    // ---- Lightweight-key bin sort + fused fine-sort/payload-apply ----
    hist2d_kernel<<<NBLK, 256, 0, stream>>>(dsti, histmatT, E, nbins, chunk);
    colsum_kernel<<<(nbins + 255) / 256, 256, 0, stream>>>(histmatT, bincnt,
                                                           segsum, nbins);
    bin_scan_kernel<<<1, 1024, 0, stream>>>(bincnt, binstart, nbins, E);
    rowscan_kernel<<<dim3((nbins + 255) / 256, NSEG), 256, 0, stream>>>(
        histmatT, binstart, segsum, basemat, nbins);
    place_kernel<<<NBLK, 512, 0, stream>>>(dsti, basemat, tmp_word,
                                           E, nbins, chunk);
    pass2_kernel<<<nbins, 512, 0, stream>>>(binstart, tmp_word, srci, ea,
                                            rowstart, src_sorted, ea_sorted,
                                            N, E);

    // ---- Layers (node-parallel depth-1 pipelined waves; temporal loads) ----
    // layer 1: wave = 4 nodes x (C=8 x S=2), 16 nodes/block
    gine_layer_wave<32, 8, 2, 4, false><<<(N + 15) / 16, 256, 0, stream>>>(
        x, rowstart, src_sorted, ea_sorted,
        (const float*)d_in[3], (const float*)d_in[4],
        (const float*)d_in[5], (const float*)d_in[6],
        (const float*)d_in[7], (const float*)d_in[8],
        (const float*)d_in[9], (const float*)d_in[10],
        (const float*)d_in[11], (const float*)d_in[12], h1, N);

    // layers 2/3: wave = 8 nodes x (C=4 x S=2), 32 nodes/block
    gine_layer_wave<16, 4, 2, 8, true><<<(N + 31) / 32, 256, 0, stream>>>(
        h1, rowstart, src_sorted, ea_sorted,
        (const float*)d_in[13], (const float*)d_in[14],
        (const float*)d_in[15], (const float*)d_in[16],
        (const float*)d_in[17], (const float*)d_in[18],
        (const float*)d_in[19], (const float*)d_in[20],
        (const float*)d_in[21], (const float*)d_in[22], h2, N);

    gine_layer_wave<16, 4, 2, 8, true><<<(N + 31) / 32, 256, 0, stream>>>(
        h2, rowstart, src_sorted, ea_sorted,
        (const float*)d_in[23], (const float*)d_in[24],
        (const float*)d_in[25], (const float*)d_in[26],
        (const float*)d_in[27], (const float*)d_in[28],
        (const float*)d_in[29], (const float*)d_in[30],
        (const float*)d_in[31], (const float*)d_in[32], h3, N);

    // ---- Head ----
    final_kernel<<<(N + 63) / 64, 256, 0, stream>>>(
        h1, h2, h3, lw1, lb1, lw2, lb2, (float*)d_out, N);
}